// Round 2
// baseline (4082.323 us; speedup 1.0000x reference)
//
#include <hip/hip_runtime.h>
#include <hip/hip_bf16.h>

#define H 128
#define NT 4
#define N3 384

__device__ __forceinline__ float bf2f(unsigned short u) {
    union { unsigned int i; float f; } v;
    v.i = ((unsigned int)u) << 16;
    return v.f;
}

__device__ __forceinline__ unsigned short f2bf(float f) {
    union { float f; unsigned int i; } v;
    v.f = f;
    unsigned int x = v.i;
    unsigned int r = (x + 0x7fffu + ((x >> 16) & 1u)) >> 16;  // RNE
    return (unsigned short)r;
}

__device__ __forceinline__ float sigmoidf_(float x) {
    return 1.0f / (1.0f + expf(-x));
}

// ---------------------------------------------------------------------------
// dtype detector: interpret low u16 of each 32-bit word of `states` as bf16.
// bf16-packed data -> sane exponents (~100%); f32 data -> low mantissa bits,
// uniform random (~25% sane). flag=1 means inputs are bf16.
// ---------------------------------------------------------------------------
__global__ void detect_dtype(const unsigned short* __restrict__ states_u16,
                             int* __restrict__ flag) {
    __shared__ int cnt;
    if (threadIdx.x == 0) cnt = 0;
    __syncthreads();
    int local = 0;
    for (int i = threadIdx.x; i < 1024; i += 256) {
        unsigned short u = states_u16[2 * i];
        int e = (u >> 7) & 0xFF;
        if (e >= 96 && e <= 158) local++;
    }
    atomicAdd(&cnt, local);
    __syncthreads();
    if (threadIdx.x == 0) *flag = (cnt >= 512) ? 1 : 0;
}

// ---------------------------------------------------------------------------
// dtype-adaptive cast to fp32 workspace
// ---------------------------------------------------------------------------
__global__ void cast_to_f32(const void* __restrict__ in,
                            float* __restrict__ out, int n,
                            const int* __restrict__ flag) {
    int i = blockIdx.x * blockDim.x + threadIdx.x;
    if (i >= n) return;
    if (*flag)
        out[i] = bf2f(((const unsigned short*)in)[i]);
    else
        out[i] = ((const float*)in)[i];
}

// ---------------------------------------------------------------------------
// M[t][n][c] = sum_k h[n][k] * W[t][k][c] + b[t][c]   (output bf16 internal)
// grid: ((NN+31)/32, NT), block: 256 = 32 nodes x 8 colgroups(16 cols each)
// ---------------------------------------------------------------------------
__global__ __launch_bounds__(256) void msg_gemm(
    const float* __restrict__ h,     // [NN][H] fp32
    const float* __restrict__ W,     // [NT][H][H] fp32 (this layer)
    const float* __restrict__ b,     // [NT][H]    fp32 (this layer)
    unsigned short* __restrict__ M,  // [NT][NN][H] bf16
    int NN) {
    __shared__ float hs[32][H + 1];

    const int t = blockIdx.y;
    const int n0 = blockIdx.x * 32;
    const int tid = threadIdx.x;

    for (int i = tid; i < 32 * H; i += 256) {
        int r = i >> 7, c = i & (H - 1);
        int n = n0 + r;
        hs[r][c] = (n < NN) ? h[(size_t)n * H + c] : 0.0f;
    }
    __syncthreads();

    const int node = tid >> 3;
    const int cg = tid & 7;
    const int col0 = cg * 16;

    float acc[16];
#pragma unroll
    for (int j = 0; j < 16; j++) acc[j] = 0.0f;

    const float* Wt = W + (size_t)t * H * H + col0;

    for (int k = 0; k < H; k++) {
        const float hv = hs[node][k];
        const float* wr = Wt + (size_t)k * H;
        float4 w0 = *(const float4*)(wr + 0);
        float4 w1 = *(const float4*)(wr + 4);
        float4 w2 = *(const float4*)(wr + 8);
        float4 w3 = *(const float4*)(wr + 12);
        acc[0]  += hv * w0.x; acc[1]  += hv * w0.y;
        acc[2]  += hv * w0.z; acc[3]  += hv * w0.w;
        acc[4]  += hv * w1.x; acc[5]  += hv * w1.y;
        acc[6]  += hv * w1.z; acc[7]  += hv * w1.w;
        acc[8]  += hv * w2.x; acc[9]  += hv * w2.y;
        acc[10] += hv * w2.z; acc[11] += hv * w2.w;
        acc[12] += hv * w3.x; acc[13] += hv * w3.y;
        acc[14] += hv * w3.z; acc[15] += hv * w3.w;
    }

    const int n = n0 + node;
    if (n < NN) {
        const float* bt = b + t * H + col0;
        unsigned short* mrow = M + ((size_t)t * NN + n) * H + col0;
#pragma unroll
        for (int j = 0; j < 16; j++) mrow[j] = f2bf(acc[j] + bt[j]);
    }
}

// ---------------------------------------------------------------------------
// agg[dst] += M[etype][src]   (fp32 atomic scatter, 4 cols per thread)
// ---------------------------------------------------------------------------
__global__ __launch_bounds__(256) void scatter_edges(
    const unsigned short* __restrict__ M,  // [NT][NN][H] bf16
    const int* __restrict__ edges,         // [NE][3] (etype, src, dst)
    float* __restrict__ agg,               // [NN][H] fp32 (pre-zeroed)
    int NE, int NN) {
    long gid = (long)blockIdx.x * 256 + threadIdx.x;
    int e = (int)(gid >> 5);
    if (e >= NE) return;
    int cg = (int)(gid & 31);

    int et  = edges[3 * e + 0];
    int src = edges[3 * e + 1];
    int dst = edges[3 * e + 2];

    const unsigned short* mrow = M + ((size_t)et * NN + src) * H + cg * 4;
    ushort4 m4 = *(const ushort4*)mrow;

    float* arow = agg + (size_t)dst * H + cg * 4;
    atomicAdd(arow + 0, bf2f(m4.x));
    atomicAdd(arow + 1, bf2f(m4.y));
    atomicAdd(arow + 2, bf2f(m4.z));
    atomicAdd(arow + 3, bf2f(m4.w));
}

// ---------------------------------------------------------------------------
// Fused GRU cell. grid: (NN+15)/16, block: 256 = 16 nodes x 16 cg (8 cols)
// Output write is dtype-adaptive via flag.
// ---------------------------------------------------------------------------
__global__ __launch_bounds__(256) void gru_fused(
    const float* __restrict__ agg,   // [NN][H]
    const float* __restrict__ h,     // [NN][H]
    const float* __restrict__ gk,    // [H][3H] fp32 (this layer)
    const float* __restrict__ gr,    // [H][3H] fp32 (this layer)
    const float* __restrict__ gb,    // [2][3H] fp32 (this layer)
    float* __restrict__ hnext,       // [NN][H] fp32
    void* __restrict__ outbuf,       // final output or nullptr
    const int* __restrict__ flag,    // 1 = bf16 output
    int NN) {
    __shared__ float as[16][H + 1];
    __shared__ float hs[16][H + 1];

    const int n0 = blockIdx.x * 16;
    const int tid = threadIdx.x;

    for (int i = tid; i < 16 * H; i += 256) {
        int r = i >> 7, c = i & (H - 1);
        int n = n0 + r;
        float av = 0.0f, hv = 0.0f;
        if (n < NN) {
            av = agg[(size_t)n * H + c];
            hv = h[(size_t)n * H + c];
        }
        as[r][c] = av;
        hs[r][c] = hv;
    }
    __syncthreads();

    const int node = tid >> 4;
    const int cg = tid & 15;
    const int col0 = cg * 8;

    float zreg[8], rreg[8];

    for (int chunk = 0; chunk < 3; chunk++) {
        float mxs[8], mhs[8];
#pragma unroll
        for (int j = 0; j < 8; j++) { mxs[j] = 0.0f; mhs[j] = 0.0f; }

        const float* gkc = gk + chunk * H + col0;
        const float* grc = gr + chunk * H + col0;

        for (int k = 0; k < H; k++) {
            const float av = as[node][k];
            const float hv = hs[node][k];
            const float* krow = gkc + (size_t)k * N3;
            const float* rrow = grc + (size_t)k * N3;
            float4 ka = *(const float4*)(krow + 0);
            float4 kb = *(const float4*)(krow + 4);
            float4 ra = *(const float4*)(rrow + 0);
            float4 rb = *(const float4*)(rrow + 4);
            mxs[0] += av * ka.x; mxs[1] += av * ka.y;
            mxs[2] += av * ka.z; mxs[3] += av * ka.w;
            mxs[4] += av * kb.x; mxs[5] += av * kb.y;
            mxs[6] += av * kb.z; mxs[7] += av * kb.w;
            mhs[0] += hv * ra.x; mhs[1] += hv * ra.y;
            mhs[2] += hv * ra.z; mhs[3] += hv * ra.w;
            mhs[4] += hv * rb.x; mhs[5] += hv * rb.y;
            mhs[6] += hv * rb.z; mhs[7] += hv * rb.w;
        }

        const int cb = chunk * H + col0;
        if (chunk == 0) {
#pragma unroll
            for (int j = 0; j < 8; j++)
                zreg[j] = sigmoidf_((mxs[j] + gb[cb + j]) + (mhs[j] + gb[N3 + cb + j]));
        } else if (chunk == 1) {
#pragma unroll
            for (int j = 0; j < 8; j++)
                rreg[j] = sigmoidf_((mxs[j] + gb[cb + j]) + (mhs[j] + gb[N3 + cb + j]));
        } else {
            const int n = n0 + node;
            if (n < NN) {
#pragma unroll
                for (int j = 0; j < 8; j++) {
                    float cc = tanhf((mxs[j] + gb[cb + j]) +
                                     rreg[j] * (mhs[j] + gb[N3 + cb + j]));
                    float hval = hs[node][col0 + j];
                    float hn = zreg[j] * hval + (1.0f - zreg[j]) * cc;
                    size_t oi = (size_t)n * H + col0 + j;
                    hnext[oi] = hn;
                    if (outbuf) {
                        if (*flag)
                            ((unsigned short*)outbuf)[oi] = f2bf(hn);
                        else
                            ((float*)outbuf)[oi] = hn;
                    }
                }
            }
        }
    }
}

// ---------------------------------------------------------------------------
extern "C" void kernel_launch(void* const* d_in, const int* in_sizes, int n_in,
                              void* d_out, int out_size, void* d_ws, size_t ws_size,
                              hipStream_t stream) {
    const void* states = d_in[0];
    const int*  edges  = (const int*)d_in[1];
    const void* type_W = d_in[2];
    const void* type_b = d_in[3];
    const void* gruk   = d_in[4];
    const void* grur   = d_in[5];
    const void* grub   = d_in[6];

    const int NN = in_sizes[0] / H;   // 50000
    const int NE = in_sizes[1] / 3;   // 400000
    const int nW  = in_sizes[2];
    const int nb  = in_sizes[3];
    const int ngk = in_sizes[4];
    const int ngr = in_sizes[5];
    const int ngb = in_sizes[6];
    const int LAYERS = 2;

    // workspace layout (fp32 unless noted)
    int*   flag = (int*)d_ws;                       // [16] (alignment pad)
    float* hA  = (float*)d_ws + 16;                 // [NN][H]
    float* hB  = hA  + (size_t)NN * H;              // [NN][H]
    float* agg = hB  + (size_t)NN * H;              // [NN][H]
    float* Wf  = agg + (size_t)NN * H;              // [2][NT][H][H]
    float* bf_ = Wf  + nW;                          // [2][NT][H]
    float* gkf = bf_ + nb;                          // [2][H][3H]
    float* grf = gkf + ngk;                         // [2][H][3H]
    float* gbf = grf + ngr;                         // [2][2][3H]
    unsigned short* M = (unsigned short*)(gbf + ngb);  // [NT][NN][H] bf16

    detect_dtype<<<1, 256, 0, stream>>>((const unsigned short*)states, flag);

    auto cast = [&](const void* src, float* dst, int n) {
        cast_to_f32<<<(n + 255) / 256, 256, 0, stream>>>(src, dst, n, flag);
    };
    cast(states, hA, NN * H);
    cast(type_W, Wf, nW);
    cast(type_b, bf_, nb);
    cast(gruk, gkf, ngk);
    cast(grur, grf, ngr);
    cast(grub, gbf, ngb);

    for (int L = 0; L < LAYERS; L++) {
        const float* hcur = (L & 1) ? hB : hA;
        float* hnext      = (L & 1) ? hA : hB;

        dim3 g1((NN + 31) / 32, NT);
        msg_gemm<<<g1, 256, 0, stream>>>(
            hcur, Wf + (size_t)L * NT * H * H, bf_ + (size_t)L * NT * H, M, NN);

        hipMemsetAsync(agg, 0, (size_t)NN * H * sizeof(float), stream);

        long total = (long)NE * 32;
        scatter_edges<<<(int)((total + 255) / 256), 256, 0, stream>>>(
            M, edges, agg, NE, NN);

        gru_fused<<<(NN + 15) / 16, 256, 0, stream>>>(
            agg, hcur,
            gkf + (size_t)L * H * N3,
            grf + (size_t)L * H * N3,
            gbf + (size_t)L * 2 * N3,
            hnext,
            (L == LAYERS - 1) ? d_out : nullptr,
            flag,
            NN);
    }
}

// Round 3
// 509.523 us; speedup vs baseline: 8.0121x; 8.0121x over previous
//
#include <hip/hip_runtime.h>
#include <hip/hip_bf16.h>

#define H 128
#define NT 4
#define CAP 96

typedef __attribute__((ext_vector_type(8))) _Float16 half8;
typedef __attribute__((ext_vector_type(2))) _Float16 half2v;
typedef __attribute__((ext_vector_type(4))) float f32x4;

__device__ __forceinline__ float bf2f(unsigned short u) {
    union { unsigned int i; float f; } v;
    v.i = ((unsigned int)u) << 16;
    return v.f;
}

__device__ __forceinline__ unsigned short f2bf(float f) {
    union { float f; unsigned int i; } v;
    v.f = f;
    unsigned int x = v.i;
    unsigned int r = (x + 0x7fffu + ((x >> 16) & 1u)) >> 16;  // RNE
    return (unsigned short)r;
}

__device__ __forceinline__ float sigmoidf_(float x) {
    return 1.0f / (1.0f + expf(-x));
}

// flag-adaptive fp32 read from raw input buffer (1 = bf16-packed, 0 = fp32)
__device__ __forceinline__ float readf(const void* p, long i, int isbf) {
    return isbf ? bf2f(((const unsigned short*)p)[i]) : ((const float*)p)[i];
}

// ---------------------------------------------------------------------------
// dtype detector (see round-1 notes): low u16 of each dword as bf16 exponent.
// ---------------------------------------------------------------------------
__global__ void detect_dtype(const unsigned short* __restrict__ states_u16,
                             int* __restrict__ flag) {
    __shared__ int cnt;
    if (threadIdx.x == 0) cnt = 0;
    __syncthreads();
    int local = 0;
    for (int i = threadIdx.x; i < 1024; i += 256) {
        unsigned short u = states_u16[2 * i];
        int e = (u >> 7) & 0xFF;
        if (e >= 96 && e <= 158) local++;
    }
    atomicAdd(&cnt, local);
    __syncthreads();
    if (threadIdx.x == 0) *flag = (cnt >= 512) ? 1 : 0;
}

// states -> h16 (fp16)
__global__ void cast_h16(const void* __restrict__ in, _Float16* __restrict__ out,
                         const int* __restrict__ flag, int n) {
    int i = blockIdx.x * blockDim.x + threadIdx.x;
    if (i < n) out[i] = (_Float16)readf(in, i, *flag);
}

// type_W [L*NT][k:128][c:128] -> WT16 [L*NT][c:128][k:128] fp16
__global__ void prep_WT(const void* __restrict__ W, _Float16* __restrict__ WT,
                        const int* __restrict__ flag, int total) {
    int i = blockIdx.x * blockDim.x + threadIdx.x;
    if (i >= total) return;
    int mat = i >> 14;           // L*NT + t
    int rem = i & 16383;
    int c = rem >> 7, k = rem & 127;
    WT[i] = (_Float16)readf(W, ((long)mat << 14) + k * H + c, *flag);
}

// gru kernel [L][k:128][c:384] -> gT [L][c:384][k:128] fp16
__global__ void prep_gT(const void* __restrict__ g, _Float16* __restrict__ gT,
                        const int* __restrict__ flag, int total) {
    int i = blockIdx.x * blockDim.x + threadIdx.x;
    if (i >= total) return;
    int L = i / 49152, rem = i % 49152;
    int c = rem >> 7, k = rem & 127;
    gT[i] = (_Float16)readf(g, (long)L * 49152 + k * 384 + c, *flag);
}

// biases -> fp32 ws; gbsum[L][384] = gb[L][0][c] + gb[L][1][c]
__global__ void prep_bias(const void* __restrict__ type_b, const void* __restrict__ grub,
                          float* __restrict__ bf_, float* __restrict__ gbf,
                          float* __restrict__ gbsum, const int* __restrict__ flag) {
    int i = blockIdx.x * blockDim.x + threadIdx.x;
    int fl = *flag;
    if (i < 1024) bf_[i] = readf(type_b, i, fl);
    if (i < 1536) gbf[i] = readf(grub, i, fl);
    if (i < 768) {
        int L = i / 384, c = i % 384;
        gbsum[i] = readf(grub, (long)L * 768 + c, fl) +
                   readf(grub, (long)L * 768 + 384 + c, fl);
    }
}

// ---------------------------------------------------------------------------
// bucket edges by dst (counts pre-zeroed by memset)
// ---------------------------------------------------------------------------
__global__ void place_edges(const int* __restrict__ edges, int* __restrict__ counts,
                            int* __restrict__ buckets, int NE) {
    int e = blockIdx.x * 256 + threadIdx.x;
    if (e >= NE) return;
    int t = edges[3 * e], src = edges[3 * e + 1], dst = edges[3 * e + 2];
    int slot = atomicAdd(&counts[dst], 1);
    if (slot < CAP) buckets[(size_t)dst * CAP + slot] = src | (t << 17);
}

// ---------------------------------------------------------------------------
// msg GEMM (MFMA): M[t][n][c] = sum_k h16[n][k] * W[t][k][c] + b[t][c]
// grid ((NN+63)/64, NT), block 256 = 4 waves; wave w: nodes w*16..+16 x 128c
// ---------------------------------------------------------------------------
__global__ __launch_bounds__(256, 1) void msg_mfma(
    const _Float16* __restrict__ h16,   // [NN][128]
    const _Float16* __restrict__ WTL,   // [NT][128c][128k] this layer
    const float* __restrict__ bL,       // [NT][128] fp32 this layer
    _Float16* __restrict__ M,           // [NT][NN][128]
    int NN) {
    __shared__ _Float16 As[64][H + 8];
    __shared__ _Float16 Bs[H][H + 8];
    __shared__ float bs[H];

    const int t = blockIdx.y;
    const int n0 = blockIdx.x * 64;
    const int tid = threadIdx.x;

    for (int i = tid; i < 1024; i += 256) {       // A: 64 x 128 / 8
        int r = i >> 4, c8 = (i & 15) * 8;
        int n = n0 + r;
        half8 v = 0;
        if (n < NN) v = *(const half8*)&h16[(size_t)n * H + c8];
        *(half8*)&As[r][c8] = v;
    }
    const _Float16* Wt = WTL + (size_t)t * H * H;
    for (int i = tid; i < 2048; i += 256) {       // B: 128 x 128 / 8
        int r = i >> 4, c8 = (i & 15) * 8;
        *(half8*)&Bs[r][c8] = *(const half8*)&Wt[r * H + c8];
    }
    if (tid < H) bs[tid] = bL[t * H + tid];
    __syncthreads();

    const int wave = tid >> 6, lane = tid & 63;
    const int m = lane & 15, quad = lane >> 4;
    const int arow = wave * 16 + m;

    f32x4 acc[8] = {};
#pragma unroll
    for (int kk = 0; kk < 4; kk++) {
        half8 a = *(const half8*)&As[arow][kk * 32 + quad * 8];
#pragma unroll
        for (int ct = 0; ct < 8; ct++) {
            half8 b = *(const half8*)&Bs[ct * 16 + m][kk * 32 + quad * 8];
            acc[ct] = __builtin_amdgcn_mfma_f32_16x16x32_f16(a, b, acc[ct], 0, 0, 0);
        }
    }

#pragma unroll
    for (int ct = 0; ct < 8; ct++) {
        int col = ct * 16 + m;
        float bias = bs[col];
#pragma unroll
        for (int i = 0; i < 4; i++) {
            int nn = n0 + wave * 16 + quad * 4 + i;
            if (nn < NN)
                M[((size_t)t * NN + nn) * H + col] = (_Float16)(acc[ct][i] + bias);
        }
    }
}

// ---------------------------------------------------------------------------
// gather: agg16[n] = sum over in-edges of M[t][src]   (one wave per node)
// ---------------------------------------------------------------------------
__global__ __launch_bounds__(256) void gather_agg(
    const _Float16* __restrict__ M, const int* __restrict__ counts,
    const int* __restrict__ buckets, _Float16* __restrict__ agg16, int NN) {
    int node = blockIdx.x * 4 + (threadIdx.x >> 6);
    int lane = threadIdx.x & 63;
    if (node >= NN) return;
    int cnt = counts[node];
    if (cnt > CAP) cnt = CAP;
    float a0 = 0.0f, a1 = 0.0f;
    const int* bkt = buckets + (size_t)node * CAP;
    for (int e = 0; e < cnt; e++) {
        int p = bkt[e];                       // wave-broadcast
        int t = p >> 17, src = p & 131071;
        half2v v = *(const half2v*)&M[((size_t)t * NN + src) * H + lane * 2];
        a0 += (float)v[0];
        a1 += (float)v[1];
    }
    half2v o;
    o[0] = (_Float16)a0;
    o[1] = (_Float16)a1;
    *(half2v*)&agg16[(size_t)node * H + lane * 2] = o;
}

// ---------------------------------------------------------------------------
// fused GRU (MFMA). grid (NN+63)/64, block 256.
// chunks 0,1 (z,r): one K=256 GEMM over [agg16|h16] x [gkT;grT]
// chunk 2 (c): xh, hh separately; epilogue blends, writes h16next (+ out)
// ---------------------------------------------------------------------------
__global__ __launch_bounds__(256, 1) void gru_mfma(
    const _Float16* __restrict__ agg16,  // [NN][128]
    const _Float16* __restrict__ h16,    // [NN][128]
    const _Float16* __restrict__ gkT,    // [384c][128k] this layer
    const _Float16* __restrict__ grT,    // [384c][128k] this layer
    const float* __restrict__ gbsumL,    // [384]
    const float* __restrict__ gbL,       // [2][384]
    _Float16* __restrict__ h16next,      // [NN][128]
    void* __restrict__ outbuf,           // final output or nullptr
    const int* __restrict__ flag, int NN) {
    __shared__ _Float16 A2[64][256 + 8];
    __shared__ _Float16 B2[H][256 + 8];

    const int n0 = blockIdx.x * 64;
    const int tid = threadIdx.x;

    for (int i = tid; i < 2048; i += 256) {       // A2: 64 x 256 / 8
        int r = i >> 5, c8 = (i & 31) * 8;
        int n = n0 + r;
        half8 v = 0;
        if (n < NN) {
            const _Float16* src = (c8 < H) ? &agg16[(size_t)n * H + c8]
                                           : &h16[(size_t)n * H + (c8 - H)];
            v = *(const half8*)src;
        }
        *(half8*)&A2[r][c8] = v;
    }

    const int wave = tid >> 6, lane = tid & 63;
    const int m = lane & 15, quad = lane >> 4;
    const int arow = wave * 16 + m;

    float zv[8][4], rv[8][4];

    for (int ch = 0; ch < 3; ch++) {
        __syncthreads();                           // B2 reuse (also covers A2 on ch=0)
        for (int i = tid; i < 4096; i += 256) {    // B2: 128 x 256 / 8
            int r = i >> 5, c8 = (i & 31) * 8;
            const _Float16* src = (c8 < H) ? &gkT[(size_t)(ch * H + r) * H + c8]
                                           : &grT[(size_t)(ch * H + r) * H + (c8 - H)];
            *(half8*)&B2[r][c8] = *(const half8*)src;
        }
        __syncthreads();

        if (ch < 2) {
            f32x4 acc[8] = {};
#pragma unroll
            for (int kk = 0; kk < 8; kk++) {
                half8 a = *(const half8*)&A2[arow][kk * 32 + quad * 8];
#pragma unroll
                for (int ct = 0; ct < 8; ct++) {
                    half8 b = *(const half8*)&B2[ct * 16 + m][kk * 32 + quad * 8];
                    acc[ct] = __builtin_amdgcn_mfma_f32_16x16x32_f16(a, b, acc[ct], 0, 0, 0);
                }
            }
#pragma unroll
            for (int ct = 0; ct < 8; ct++) {
                float bias = gbsumL[ch * H + ct * 16 + m];
#pragma unroll
                for (int i = 0; i < 4; i++) {
                    float g = sigmoidf_(acc[ct][i] + bias);
                    if (ch == 0) zv[ct][i] = g; else rv[ct][i] = g;
                }
            }
        } else {
            f32x4 xh[8] = {}, hh[8] = {};
#pragma unroll
            for (int kk = 0; kk < 4; kk++) {
                half8 ax = *(const half8*)&A2[arow][kk * 32 + quad * 8];
                half8 ah = *(const half8*)&A2[arow][H + kk * 32 + quad * 8];
#pragma unroll
                for (int ct = 0; ct < 8; ct++) {
                    half8 bx = *(const half8*)&B2[ct * 16 + m][kk * 32 + quad * 8];
                    half8 bh = *(const half8*)&B2[ct * 16 + m][H + kk * 32 + quad * 8];
                    xh[ct] = __builtin_amdgcn_mfma_f32_16x16x32_f16(ax, bx, xh[ct], 0, 0, 0);
                    hh[ct] = __builtin_amdgcn_mfma_f32_16x16x32_f16(ah, bh, hh[ct], 0, 0, 0);
                }
            }
            const int fl = outbuf ? *flag : 0;
#pragma unroll
            for (int ct = 0; ct < 8; ct++) {
                int col = ct * 16 + m;
                float b0 = gbL[256 + col];
                float b1 = gbL[384 + 256 + col];
#pragma unroll
                for (int i = 0; i < 4; i++) {
                    int row = wave * 16 + quad * 4 + i;
                    int nn = n0 + row;
                    if (nn < NN) {
                        float hv = (float)A2[row][H + col];
                        float cc = tanhf((xh[ct][i] + b0) + rv[ct][i] * (hh[ct][i] + b1));
                        float hn = zv[ct][i] * hv + (1.0f - zv[ct][i]) * cc;
                        size_t oi = (size_t)nn * H + col;
                        h16next[oi] = (_Float16)hn;
                        if (outbuf) {
                            if (fl) ((unsigned short*)outbuf)[oi] = f2bf(hn);
                            else    ((float*)outbuf)[oi] = hn;
                        }
                    }
                }
            }
        }
    }
}

// ---------------------------------------------------------------------------
extern "C" void kernel_launch(void* const* d_in, const int* in_sizes, int n_in,
                              void* d_out, int out_size, void* d_ws, size_t ws_size,
                              hipStream_t stream) {
    const void* states = d_in[0];
    const int*  edges  = (const int*)d_in[1];
    const void* type_W = d_in[2];
    const void* type_b = d_in[3];
    const void* gruk   = d_in[4];
    const void* grur   = d_in[5];
    const void* grub   = d_in[6];

    const int NN = in_sizes[0] / H;    // 50000
    const int NE = in_sizes[1] / 3;    // 400000
    const int nW = in_sizes[2];        // L*NT*128*128
    const int LAYERS = nW / (NT * H * H);

    // --- workspace layout ---
    char* w = (char*)d_ws;
    int* flag = (int*)w;                              w += 64;
    _Float16* h16A  = (_Float16*)w;                   w += (size_t)NN * H * 2;
    _Float16* h16B  = (_Float16*)w;                   w += (size_t)NN * H * 2;
    _Float16* agg16 = (_Float16*)w;                   w += (size_t)NN * H * 2;
    _Float16* M     = (_Float16*)w;                   w += (size_t)NT * NN * H * 2;
    _Float16* WT16  = (_Float16*)w;                   w += (size_t)nW * 2;
    _Float16* gkT16 = (_Float16*)w;                   w += (size_t)LAYERS * 384 * H * 2;
    _Float16* grT16 = (_Float16*)w;                   w += (size_t)LAYERS * 384 * H * 2;
    float* bf_   = (float*)w;                         w += (size_t)LAYERS * NT * H * 4;
    float* gbf   = (float*)w;                         w += (size_t)LAYERS * 2 * 384 * 4;
    float* gbsum = (float*)w;                         w += (size_t)LAYERS * 384 * 4;
    int* counts  = (int*)w;                           w += (size_t)NN * 4;
    int* buckets = (int*)w;                           // [NN][CAP]

    detect_dtype<<<1, 256, 0, stream>>>((const unsigned short*)states, flag);

    cast_h16<<<(NN * H + 255) / 256, 256, 0, stream>>>(states, h16A, flag, NN * H);
    prep_WT<<<(nW + 255) / 256, 256, 0, stream>>>(type_W, WT16, flag, nW);
    const int ng = LAYERS * 384 * H;
    prep_gT<<<(ng + 255) / 256, 256, 0, stream>>>(gruk, gkT16, flag, ng);
    prep_gT<<<(ng + 255) / 256, 256, 0, stream>>>(grur, grT16, flag, ng);
    prep_bias<<<6, 256, 0, stream>>>(type_b, grub, bf_, gbf, gbsum, flag);

    hipMemsetAsync(counts, 0, (size_t)NN * 4, stream);
    place_edges<<<(NE + 255) / 256, 256, 0, stream>>>(edges, counts, buckets, NE);

    const int ntile = (NN + 63) / 64;
    for (int L = 0; L < LAYERS; L++) {
        const _Float16* hcur = (L & 1) ? h16B : h16A;
        _Float16* hnext      = (L & 1) ? h16A : h16B;

        dim3 g1(ntile, NT);
        msg_mfma<<<g1, 256, 0, stream>>>(
            hcur, WT16 + (size_t)L * NT * H * H, bf_ + (size_t)L * NT * H, M, NN);

        gather_agg<<<(NN + 3) / 4, 256, 0, stream>>>(M, counts, buckets, agg16, NN);

        gru_mfma<<<ntile, 256, 0, stream>>>(
            agg16, hcur,
            gkT16 + (size_t)L * 384 * H,
            grT16 + (size_t)L * 384 * H,
            gbsum + (size_t)L * 384,
            gbf + (size_t)L * 2 * 384,
            hnext,
            (L == LAYERS - 1) ? d_out : nullptr,
            flag, NN);
    }
}